// Round 6
// baseline (254.517 us; speedup 1.0000x reference)
//
#include <hip/hip_runtime.h>

// SmoothL1 (beta=0.5) masked sum reduction, N = 16M fixed.
// sl1 = ad < 0.5 ? d*d : ad - 0.25  (0.5*d*d/0.5 == d*d exactly: pow-2)
// mask: ad >= 1.0f/len; out[0] = sum(mask ? sl1 : 0)
//
// R5 -> R6: three MLP experiments all neutral; effective read BW pins at
// 4.23 TB/s (~220 B/cyc/XCD) and is invariant to HBM-vs-cache sourcing =>
// request-path service cap. Last cheap lever: dispatch granularity. 8192
// blocks x 2 vec4 iters (4-deep block queue per CU slot) smooths XCD
// dispatch skew and ramp/drain, which a 47us kernel can't amortize at
// exactly-8-resident-blocks granularity. nt loads kept (R4's 1.5x win:
// avoids L2 write-allocation thrash).

#define N_TOTAL 16777216
#define NVEC    (N_TOTAL / 4)   // 4194304 vec4 groups
#define BLOCK   256
#define GRID    8192            // 2 iters/thread, 4-deep block queue per CU slot
#define UNROLL  2

typedef float f32x4 __attribute__((ext_vector_type(4)));
typedef int   i32x4 __attribute__((ext_vector_type(4)));

__device__ __forceinline__ float sl1_term(float o, float l, int len) {
    float d  = o - l;
    float ad = fabsf(d);
    float v  = (ad < 0.5f) ? (d * d) : (ad - 0.25f);
    float boundary = 1.0f / (float)len;   // IEEE divide; matches jnp 1/len
    return (ad >= boundary) ? v : 0.0f;
}

__global__ __launch_bounds__(BLOCK) void RegressionLoss_45440753992375_kernel(
        const float* __restrict__ outs,
        const float* __restrict__ labels,
        const int*   __restrict__ lens,
        float* __restrict__ out) {
    const f32x4* o4 = (const f32x4*)outs;
    const f32x4* l4 = (const f32x4*)labels;
    const i32x4* n4 = (const i32x4*)lens;

    // Block-contiguous: block b owns vec4 range [b*512, (b+1)*512).
    const int base = blockIdx.x * (BLOCK * UNROLL) + threadIdx.x;

    // Batch all 6 nt loads up front.
    f32x4 o[UNROLL], l[UNROLL];
    i32x4 ln[UNROLL];
    #pragma unroll
    for (int u = 0; u < UNROLL; ++u) o[u]  = __builtin_nontemporal_load(o4 + base + u * BLOCK);
    #pragma unroll
    for (int u = 0; u < UNROLL; ++u) l[u]  = __builtin_nontemporal_load(l4 + base + u * BLOCK);
    #pragma unroll
    for (int u = 0; u < UNROLL; ++u) ln[u] = __builtin_nontemporal_load(n4 + base + u * BLOCK);

    float a0 = 0.0f, a1 = 0.0f;
    a0 += sl1_term(o[0].x, l[0].x, ln[0].x);
    a1 += sl1_term(o[0].y, l[0].y, ln[0].y);
    a0 += sl1_term(o[0].z, l[0].z, ln[0].z);
    a1 += sl1_term(o[0].w, l[0].w, ln[0].w);
    a0 += sl1_term(o[1].x, l[1].x, ln[1].x);
    a1 += sl1_term(o[1].y, l[1].y, ln[1].y);
    a0 += sl1_term(o[1].z, l[1].z, ln[1].z);
    a1 += sl1_term(o[1].w, l[1].w, ln[1].w);
    float acc = a0 + a1;

    // wave-64 shuffle reduction
    #pragma unroll
    for (int off = 32; off > 0; off >>= 1)
        acc += __shfl_down(acc, off, 64);

    __shared__ float smem[BLOCK / 64];
    const int lane = threadIdx.x & 63;
    const int wid  = threadIdx.x >> 6;
    if (lane == 0) smem[wid] = acc;
    __syncthreads();
    if (threadIdx.x == 0) {
        float bsum = smem[0] + smem[1] + smem[2] + smem[3];
        atomicAdd(out, bsum);   // device-scope by default on CDNA
    }
}

extern "C" void kernel_launch(void* const* d_in, const int* in_sizes, int n_in,
                              void* d_out, int out_size, void* d_ws, size_t ws_size,
                              hipStream_t stream) {
    const float* outs   = (const float*)d_in[0];
    const float* labels = (const float*)d_in[1];
    const int*   lens   = (const int*)d_in[2];
    float* out = (float*)d_out;

    // d_out is poisoned 0xAA before every timed launch — zero it on-stream.
    hipMemsetAsync(out, 0, sizeof(float), stream);

    RegressionLoss_45440753992375_kernel<<<GRID, BLOCK, 0, stream>>>(outs, labels, lens, out);
}

// Round 7
// 188.445 us; speedup vs baseline: 1.3506x; 1.3506x over previous
//
#include <hip/hip_runtime.h>

// SmoothL1 (beta=0.5) masked sum reduction, N = 16M fixed.
// sl1 = ad < 0.5 ? d*d : ad - 0.25  (0.5*d*d/0.5 == d*d exactly: pow-2)
// mask: ad >= 1.0f/len; out[0] = sum(mask ? sl1 : 0)
//
// R6 -> R7: R6 (8192x2) regressed 2.4x — too little work per block to hide
// latency + per-block epilogue. Revert to R5 structure (2048 blocks x 8 iters,
// 47.5us, 4.23 TB/s effective). This round's single diff: mixed-path loads.
// lens -> regular cached loads (67 MB), outs/labels -> nt (134 MB). Tests
// whether the ~4.2 TB/s cap is nt-path-specific (win ~38us) or a shared
// XCD-port cap (neutral) or allocation-pollution returns (regress).

#define N_TOTAL 16777216
#define NVEC    (N_TOTAL / 4)       // 4194304 vec4 groups
#define BLOCK   256
#define GRID    2048                // 8 blocks/CU, 32 waves/CU
#define ITERS   (NVEC / (BLOCK * GRID))   // 8 iterations/thread, exact cover

typedef float f32x4 __attribute__((ext_vector_type(4)));
typedef int   i32x4 __attribute__((ext_vector_type(4)));

__device__ __forceinline__ float sl1_term(float o, float l, int len) {
    float d  = o - l;
    float ad = fabsf(d);
    float v  = (ad < 0.5f) ? (d * d) : (ad - 0.25f);
    float boundary = 1.0f / (float)len;   // IEEE divide; matches jnp 1/len
    return (ad >= boundary) ? v : 0.0f;
}

__global__ __launch_bounds__(BLOCK) void RegressionLoss_45440753992375_kernel(
        const float* __restrict__ outs,
        const float* __restrict__ labels,
        const int*   __restrict__ lens,
        float* __restrict__ out) {
    const f32x4* o4 = (const f32x4*)outs;
    const f32x4* l4 = (const f32x4*)labels;
    const i32x4* n4 = (const i32x4*)lens;

    // Block-contiguous: block b owns [b*BLOCK*ITERS, ...), thread strides BLOCK.
    int i = blockIdx.x * (BLOCK * ITERS) + threadIdx.x;

    // Pipeline stage 0. outs/labels: nt path; lens: regular cached path.
    f32x4 o_c = __builtin_nontemporal_load(o4 + i);
    f32x4 l_c = __builtin_nontemporal_load(l4 + i);
    i32x4 n_c = n4[i];

    float acc = 0.0f;
    #pragma unroll
    for (int it = 0; it < ITERS - 1; ++it) {
        i += BLOCK;
        // Issue next-iteration loads BEFORE consuming current registers.
        f32x4 o_n = __builtin_nontemporal_load(o4 + i);
        f32x4 l_n = __builtin_nontemporal_load(l4 + i);
        i32x4 n_n = n4[i];

        acc += sl1_term(o_c.x, l_c.x, n_c.x);
        acc += sl1_term(o_c.y, l_c.y, n_c.y);
        acc += sl1_term(o_c.z, l_c.z, n_c.z);
        acc += sl1_term(o_c.w, l_c.w, n_c.w);

        o_c = o_n; l_c = l_n; n_c = n_n;
    }
    acc += sl1_term(o_c.x, l_c.x, n_c.x);
    acc += sl1_term(o_c.y, l_c.y, n_c.y);
    acc += sl1_term(o_c.z, l_c.z, n_c.z);
    acc += sl1_term(o_c.w, l_c.w, n_c.w);

    // wave-64 shuffle reduction
    #pragma unroll
    for (int off = 32; off > 0; off >>= 1)
        acc += __shfl_down(acc, off, 64);

    __shared__ float smem[BLOCK / 64];
    const int lane = threadIdx.x & 63;
    const int wid  = threadIdx.x >> 6;
    if (lane == 0) smem[wid] = acc;
    __syncthreads();
    if (threadIdx.x == 0) {
        float bsum = smem[0] + smem[1] + smem[2] + smem[3];
        atomicAdd(out, bsum);   // device-scope by default on CDNA
    }
}

extern "C" void kernel_launch(void* const* d_in, const int* in_sizes, int n_in,
                              void* d_out, int out_size, void* d_ws, size_t ws_size,
                              hipStream_t stream) {
    const float* outs   = (const float*)d_in[0];
    const float* labels = (const float*)d_in[1];
    const int*   lens   = (const int*)d_in[2];
    float* out = (float*)d_out;

    // d_out is poisoned 0xAA before every timed launch — zero it on-stream.
    hipMemsetAsync(out, 0, sizeof(float), stream);

    RegressionLoss_45440753992375_kernel<<<GRID, BLOCK, 0, stream>>>(outs, labels, lens, out);
}